// Round 14
// baseline (256.297 us; speedup 1.0000x reference)
//
#include <hip/hip_runtime.h>
#include <cstdint>

// FeaturePropagation: BL=16, N=8192, N_sub=2048, dim=256, K=3, f32.
// R9..R12 invariance (119-124us vs VALU 14..31/cand, waves 2..4/SIMD) =>
// binder is the per-wave-iteration LDS read + dependent chain; iteration
// count queries*cands/64 = 4.19M was constant. R13: 4 QUERIES PER THREAD --
// one ds_read_b128 feeds 4 independent dist+insert chains; wave-iterations
// drop to 1.05M (LDS /4) and per-iteration ILP covers latency.
// Selection pipeline unchanged (truncated-key top-6 per quarter -> merge ->
// f64 re-rank; proven R4..R12).

#define NBL   16
#define NQ    8192
#define NS    2048
#define DIM   256
#define TPB   256   // threads per block
#define QPB   256   // queries per block (slot = tid&63 owns 4, quarter = tid>>6)

typedef float __attribute__((ext_vector_type(4))) f32x4;

// Branchless sorted-6 insert, ONE asm block (8 VALU). carry-first per pair.
#define INS6(K0,K1,K2,K3,K4,K5,CUR)                                        \
    {   int cc = (CUR), ct;                                                \
        asm("v_max_i32 %[ct], %[k1], %[cc]\n\t"                            \
            "v_med3_i32 %[k1], %[k0], %[k1], %[cc]\n\t"                    \
            "v_min_i32 %[k0], %[k0], %[cc]\n\t"                            \
            "v_max_i32 %[cc], %[k3], %[ct]\n\t"                            \
            "v_med3_i32 %[k3], %[k2], %[k3], %[ct]\n\t"                    \
            "v_min_i32 %[k2], %[k2], %[ct]\n\t"                            \
            "v_med3_i32 %[k5], %[k4], %[k5], %[cc]\n\t"                    \
            "v_min_i32 %[k4], %[k4], %[cc]"                                \
            : [k0] "+v"(K0), [k1] "+v"(K1), [k2] "+v"(K2),                 \
              [k3] "+v"(K3), [k4] "+v"(K4), [k5] "+v"(K5),                 \
              [cc] "+v"(cc), [ct] "=&v"(ct)                                \
            :);                                                            \
    }

__global__ __launch_bounds__(TPB, 2)
void fprop_kernel(const float* __restrict__ xyzs,
                  const float* __restrict__ feats,
                  const float* __restrict__ xyzo,
                  float* __restrict__ out) {
    __shared__ float4 sxyz[NS];            // 32 KiB: x, y, z, ||s||^2
    __shared__ int    mbuf[QPB][4][6];     // 24 KiB: per-query per-quarter top-6;
                                           // mbuf[qq][0][0..5] reused for results

    const int tid    = threadIdx.x;
    const int B      = blockIdx.x;
    const int xcd    = B & 7;                    // HW: XCD = blockIdx % 8
    const int blocal = B >> 3;                   // 0..63
    const int bl     = 2 * xcd + (blocal >> 5);  // 2 bl's per XCD
    const int qbase  = (blocal & 31) * QPB;

    // ---- Phase 0: stage candidates into LDS ----
    const float* xs = xyzs + (size_t)bl * NS * 3;
    for (int c = tid; c < NS; c += TPB) {
        float x = xs[c * 3 + 0];
        float y = xs[c * 3 + 1];
        float z = xs[c * 3 + 2];
        sxyz[c] = make_float4(x, y, z, fmaf(x, x, fmaf(y, y, z * z)));
    }
    __syncthreads();

    const int q = tid & 63;                      // query slot: owns queries 4q..4q+3
    const int h = tid >> 6;                      // quarter 0..3 (wave-uniform)

    // ---- Phase 1: quarter-scan, 4 queries per thread ----
    {
        // load 4 queries' coords as 3 x float4 (16B-aligned: 48B per slot)
        const float4* qp = (const float4*)(xyzo + ((size_t)bl * NQ + qbase + q * 4) * 3);
        const float4 qA = qp[0], qB = qp[1], qC = qp[2];
        const float x0 = qA.x, y0 = qA.y, z0 = qA.z;
        const float x1 = qA.w, y1 = qB.x, z1 = qB.y;
        const float x2 = qB.z, y2 = qB.w, z2 = qC.x;
        const float x3 = qC.y, y3 = qC.z, z3 = qC.w;
        const float a0 = fmaf(x0, x0, fmaf(y0, y0, z0 * z0));
        const float a1 = fmaf(x1, x1, fmaf(y1, y1, z1 * z1));
        const float a2 = fmaf(x2, x2, fmaf(y2, y2, z2 * z2));
        const float a3 = fmaf(x3, x3, fmaf(y3, y3, z3 * z3));
        const float nx0 = -2.0f * x0, ny0 = -2.0f * y0, nz0 = -2.0f * z0;
        const float nx1 = -2.0f * x1, ny1 = -2.0f * y1, nz1 = -2.0f * z1;
        const float nx2 = -2.0f * x2, ny2 = -2.0f * y2, nz2 = -2.0f * z2;
        const float nx3 = -2.0f * x3, ny3 = -2.0f * y3, nz3 = -2.0f * z3;

        int ka0 = 0x7FFFFFFF, ka1 = 0x7FFFFFFF, ka2 = 0x7FFFFFFF,
            ka3 = 0x7FFFFFFF, ka4 = 0x7FFFFFFF, ka5 = 0x7FFFFFFF;
        int kb0 = 0x7FFFFFFF, kb1 = 0x7FFFFFFF, kb2 = 0x7FFFFFFF,
            kb3 = 0x7FFFFFFF, kb4 = 0x7FFFFFFF, kb5 = 0x7FFFFFFF;
        int kc0 = 0x7FFFFFFF, kc1 = 0x7FFFFFFF, kc2 = 0x7FFFFFFF,
            kc3 = 0x7FFFFFFF, kc4 = 0x7FFFFFFF, kc5 = 0x7FFFFFFF;
        int kd0 = 0x7FFFFFFF, kd1 = 0x7FFFFFFF, kd2 = 0x7FFFFFFF,
            kd3 = 0x7FFFFFFF, kd4 = 0x7FFFFFFF, kd5 = 0x7FFFFFFF;

        const int cbase = h << 9;                // h * 512

#pragma unroll 2
        for (int c = 0; c < NS / 4; ++c) {
            const float4 s = sxyz[cbase + c];
            const int idx = cbase + c;
            const float t0 = fmaf(nx0, s.x, fmaf(ny0, s.y, fmaf(nz0, s.z, a0 + s.w)));
            const float t1 = fmaf(nx1, s.x, fmaf(ny1, s.y, fmaf(nz1, s.z, a1 + s.w)));
            const float t2 = fmaf(nx2, s.x, fmaf(ny2, s.y, fmaf(nz2, s.z, a2 + s.w)));
            const float t3 = fmaf(nx3, s.x, fmaf(ny3, s.y, fmaf(nz3, s.z, a3 + s.w)));
            const int c0 = (int)((__float_as_uint(t0) & 0xFFFFF800u) | (uint32_t)idx);
            const int c1 = (int)((__float_as_uint(t1) & 0xFFFFF800u) | (uint32_t)idx);
            const int c2 = (int)((__float_as_uint(t2) & 0xFFFFF800u) | (uint32_t)idx);
            const int c3 = (int)((__float_as_uint(t3) & 0xFFFFF800u) | (uint32_t)idx);
            INS6(ka0, ka1, ka2, ka3, ka4, ka5, c0)
            INS6(kb0, kb1, kb2, kb3, kb4, kb5, c1)
            INS6(kc0, kc1, kc2, kc3, kc4, kc5, c2)
            INS6(kd0, kd1, kd2, kd3, kd4, kd5, c3)
        }
        mbuf[q*4+0][h][0]=ka0; mbuf[q*4+0][h][1]=ka1; mbuf[q*4+0][h][2]=ka2;
        mbuf[q*4+0][h][3]=ka3; mbuf[q*4+0][h][4]=ka4; mbuf[q*4+0][h][5]=ka5;
        mbuf[q*4+1][h][0]=kb0; mbuf[q*4+1][h][1]=kb1; mbuf[q*4+1][h][2]=kb2;
        mbuf[q*4+1][h][3]=kb3; mbuf[q*4+1][h][4]=kb4; mbuf[q*4+1][h][5]=kb5;
        mbuf[q*4+2][h][0]=kc0; mbuf[q*4+2][h][1]=kc1; mbuf[q*4+2][h][2]=kc2;
        mbuf[q*4+2][h][3]=kc3; mbuf[q*4+2][h][4]=kc4; mbuf[q*4+2][h][5]=kc5;
        mbuf[q*4+3][h][0]=kd0; mbuf[q*4+3][h][1]=kd1; mbuf[q*4+3][h][2]=kd2;
        mbuf[q*4+3][h][3]=kd3; mbuf[q*4+3][h][4]=kd4; mbuf[q*4+3][h][5]=kd5;
    }
    __syncthreads();

    // ---- merge: thread tid owns query qq=tid; fold 4 quarter-lists ----
    {
        const int qq = tid;
        int k0 = 0x7FFFFFFF, k1 = 0x7FFFFFFF, k2 = 0x7FFFFFFF;
        int k3 = 0x7FFFFFFF, k4 = 0x7FFFFFFF, k5 = 0x7FFFFFFF;
#pragma unroll
        for (int hh = 0; hh < 4; ++hh)
#pragma unroll
            for (int j = 0; j < 6; ++j) INS6(k0, k1, k2, k3, k4, k5, mbuf[qq][hh][j])

        int ii0 = k0 & 0x7FF, ii1 = k1 & 0x7FF, ii2 = k2 & 0x7FF;
        int ii3 = k3 & 0x7FF, ii4 = k4 & 0x7FF, ii5 = k5 & 0x7FF;
        const float* qpm = xyzo + ((size_t)bl * NQ + qbase + qq) * 3;
        const double qdx = (double)qpm[0], qdy = (double)qpm[1], qdz = (double)qpm[2];
        double dd0, dd1, dd2, dd3, dd4, dd5;
#define D2OF(JJ, DD)                                                       \
        {                                                                  \
            const float4 s = sxyz[JJ];                                     \
            const double dx = qdx - (double)s.x;                           \
            const double dy = qdy - (double)s.y;                           \
            const double dz = qdz - (double)s.z;                           \
            DD = fma(dx, dx, fma(dy, dy, dz * dz));                        \
        }
        D2OF(ii0, dd0) D2OF(ii1, dd1) D2OF(ii2, dd2)
        D2OF(ii3, dd3) D2OF(ii4, dd4) D2OF(ii5, dd5)
#undef D2OF

#define CSW(A, B)                                                          \
        {                                                                  \
            const bool sw = (dd##B < dd##A) ||                             \
                            (dd##B == dd##A && ii##B < ii##A);             \
            const double td = sw ? dd##B : dd##A;                          \
            const double tu = sw ? dd##A : dd##B;                          \
            const int    ti = sw ? ii##B : ii##A;                          \
            const int    tj = sw ? ii##A : ii##B;                          \
            dd##A = td; dd##B = tu; ii##A = ti; ii##B = tj;                \
        }
        // optimal 12-comparator sorting network, n=6 (Knuth)
        CSW(0,5) CSW(1,3) CSW(2,4)
        CSW(1,2) CSW(3,4)
        CSW(0,3) CSW(2,5)
        CSW(0,1) CSW(2,3) CSW(4,5)
        CSW(1,2) CSW(3,4)
#undef CSW

        const double w0 = 1.0 / (dd0 + 1e-6);
        const double w1 = 1.0 / (dd1 + 1e-6);
        const double w2 = 1.0 / (dd2 + 1e-6);
        const double inv = 1.0 / (w0 + w1 + w2);
        // safe: this thread already consumed mbuf[qq][*]; sole writer/reader
        mbuf[qq][0][0] = ii0; mbuf[qq][0][1] = ii1; mbuf[qq][0][2] = ii2;
        mbuf[qq][0][3] = __float_as_int((float)(w0 * inv));
        mbuf[qq][0][4] = __float_as_int((float)(w1 * inv));
        mbuf[qq][0][5] = __float_as_int((float)(w2 * inv));
    }
    __syncthreads();

    // ---- Phase 2: wave-per-query gather-blend (64 lanes x float4 = 256 dims) ----
    {
        const int wv   = tid >> 6;               // 0..3
        const int lane = tid & 63;
        const float4* fb = (const float4*)(feats + (size_t)bl * NS * DIM);
        float* ob = out + ((size_t)bl * NQ + qbase) * DIM;

#pragma unroll 2
        for (int j = wv; j < QPB; j += 4) {
            const int   i0 = mbuf[j][0][0], i1 = mbuf[j][0][1], i2 = mbuf[j][0][2];
            const float w0 = __int_as_float(mbuf[j][0][3]);
            const float w1 = __int_as_float(mbuf[j][0][4]);
            const float w2 = __int_as_float(mbuf[j][0][5]);
            const float4 f0 = fb[(size_t)i0 * (DIM / 4) + lane];
            const float4 f1 = fb[(size_t)i1 * (DIM / 4) + lane];
            const float4 f2 = fb[(size_t)i2 * (DIM / 4) + lane];
            f32x4 r;
            r.x = fmaf(w0, f0.x, fmaf(w1, f1.x, w2 * f2.x));
            r.y = fmaf(w0, f0.y, fmaf(w1, f1.y, w2 * f2.y));
            r.z = fmaf(w0, f0.z, fmaf(w1, f1.z, w2 * f2.z));
            r.w = fmaf(w0, f0.w, fmaf(w1, f1.w, w2 * f2.w));
            __builtin_nontemporal_store(
                r, (f32x4*)(ob + ((size_t)j * DIM) + lane * 4));
        }
    }
}

extern "C" void kernel_launch(void* const* d_in, const int* in_sizes, int n_in,
                              void* d_out, int out_size, void* d_ws, size_t ws_size,
                              hipStream_t stream) {
    const float* xyzs  = nullptr;  // 16*2048*3
    const float* feats = nullptr;  // 16*2048*256
    const float* xyzo  = nullptr;  // 16*8192*3
    for (int i = 0; i < n_in; ++i) {
        if      (in_sizes[i] == NBL * NS * 3)   xyzs  = (const float*)d_in[i];
        else if (in_sizes[i] == NBL * NS * DIM) feats = (const float*)d_in[i];
        else if (in_sizes[i] == NBL * NQ * 3)   xyzo  = (const float*)d_in[i];
    }
    float* out = (float*)d_out;

    dim3 grid(NBL * (NQ / QPB));                 // 512 blocks
    dim3 block(TPB);                             // 256 threads
    fprop_kernel<<<grid, block, 0, stream>>>(xyzs, feats, xyzo, out);
}

// Round 15
// 235.954 us; speedup vs baseline: 1.0862x; 1.0862x over previous
//
#include <hip/hip_runtime.h>
#include <cstdint>

// FeaturePropagation: BL=16, N=8192, N_sub=2048, dim=256, K=3, f32.
// R9-R12 invariant 119-124us across VALU 14..31/cand and 2..4 waves/SIMD;
// R14 (4q/thread) regressed to 141 (occupancy+opaque-asm confounds).
// Hidden binder hypothesis: 4.19M broadcast ds_read_b128 = ~82us/CU of LDS
// issue. R15 (ONE variable vs R12): candidates stream via the SCALAR path --
// prep kernel writes (x,y,z,||s||^2) to d_ws; scan reads with wave-uniform
// address (readfirstlane quarter base) => s_load_dwordx4 to SGPRs, no LDS /
// VMEM in the loop. Rest identical to R12 (4-way split, INS6 asm, f64
// re-rank, XCD swizzle, NT stores; selection proven R4..R12).

#define NBL   16
#define NQ    8192
#define NS    2048
#define DIM   256
#define TPB   256   // threads per block
#define QPB   64    // queries per block (4 threads per query)

typedef float __attribute__((ext_vector_type(4))) f32x4;

// Branchless sorted-6 insert, ONE asm block (8 VALU). carry-first per pair.
#define INS6(CUR)                                                          \
    {   int cc = (CUR), ct;                                                \
        asm("v_max_i32 %[ct], %[k1], %[cc]\n\t"                            \
            "v_med3_i32 %[k1], %[k0], %[k1], %[cc]\n\t"                    \
            "v_min_i32 %[k0], %[k0], %[cc]\n\t"                            \
            "v_max_i32 %[cc], %[k3], %[ct]\n\t"                            \
            "v_med3_i32 %[k3], %[k2], %[k3], %[ct]\n\t"                    \
            "v_min_i32 %[k2], %[k2], %[ct]\n\t"                            \
            "v_med3_i32 %[k5], %[k4], %[k5], %[cc]\n\t"                    \
            "v_min_i32 %[k4], %[k4], %[cc]"                                \
            : [k0] "+v"(k0), [k1] "+v"(k1), [k2] "+v"(k2),                 \
              [k3] "+v"(k3), [k4] "+v"(k4), [k5] "+v"(k5),                 \
              [cc] "+v"(cc), [ct] "=&v"(ct)                                \
            :);                                                            \
    }

// ---- prep: candidate table (x, y, z, ||s||^2) into d_ws ----
__global__ __launch_bounds__(256)
void fprep_kernel(const float* __restrict__ xyzs, float4* __restrict__ ws4) {
    const int i = blockIdx.x * 256 + threadIdx.x;      // 0 .. NBL*NS-1
    if (i < NBL * NS) {
        const float x = xyzs[3 * i + 0];
        const float y = xyzs[3 * i + 1];
        const float z = xyzs[3 * i + 2];
        ws4[i] = make_float4(x, y, z, fmaf(x, x, fmaf(y, y, z * z)));
    }
}

__global__ __launch_bounds__(TPB, 4)
void fprop_kernel(const float4* __restrict__ ws4,
                  const float* __restrict__ feats,
                  const float* __restrict__ xyzo,
                  float* __restrict__ out) {
    __shared__ int mbuf[QPB][4][6];   // 6 KiB: per-query per-quarter top-6;
                                      // mbuf[q][1][0..5] reused for results

    const int tid    = threadIdx.x;
    const int B      = blockIdx.x;
    const int xcd    = B & 7;                    // HW: XCD = blockIdx % 8
    const int blocal = B >> 3;                   // 0..255
    const int bl     = 2 * xcd + (blocal >> 7);  // 2 bl's per XCD
    const int qbase  = (blocal & 127) * QPB;

    const int q = tid & (QPB - 1);
    const int h = tid >> 6;                      // wave index 0..3 (wave-uniform)

    int k0 = 0x7FFFFFFF, k1 = 0x7FFFFFFF, k2 = 0x7FFFFFFF;
    int k3 = 0x7FFFFFFF, k4 = 0x7FFFFFFF, k5 = 0x7FFFFFFF;

    // ---- Phase 1: quarter-scan via SCALAR loads (wave-uniform address) ----
    const float* qp = xyzo + ((size_t)bl * NQ + qbase + q) * 3;
    const float qx = qp[0], qy = qp[1], qz = qp[2];
    {
        const float a2 = fmaf(qx, qx, fmaf(qy, qy, qz * qz));
        const float nx = -2.0f * qx, ny = -2.0f * qy, nz = -2.0f * qz;
        // force uniformity so the compiler emits s_load for cand[c]
        const int cbase = __builtin_amdgcn_readfirstlane(h << 9);  // h * 512
        const float4* __restrict__ cand = ws4 + (size_t)bl * NS + cbase;

#pragma unroll 4
        for (int c = 0; c < NS / 4; ++c) {
            const float4 s = cand[c];
            const float t = fmaf(nx, s.x, fmaf(ny, s.y, fmaf(nz, s.z, a2 + s.w)));
            const int cur = (int)((__float_as_uint(t) & 0xFFFFF800u) |
                                  (uint32_t)(cbase + c));
            INS6(cur)
        }
        mbuf[q][h][0] = k0; mbuf[q][h][1] = k1; mbuf[q][h][2] = k2;
        mbuf[q][h][3] = k3; mbuf[q][h][4] = k4; mbuf[q][h][5] = k5;
    }
    __syncthreads();

    // ---- wave 0 only: merge partners' lists, f64 re-rank, publish ----
    if (h == 0) {
#pragma unroll
        for (int hh = 1; hh < 4; ++hh)
#pragma unroll
            for (int j = 0; j < 6; ++j) INS6(mbuf[q][hh][j])

        int ii0 = k0 & 0x7FF, ii1 = k1 & 0x7FF, ii2 = k2 & 0x7FF;
        int ii3 = k3 & 0x7FF, ii4 = k4 & 0x7FF, ii5 = k5 & 0x7FF;
        const double qdx = (double)qx, qdy = (double)qy, qdz = (double)qz;
        const float4* cb = ws4 + (size_t)bl * NS;
        double dd0, dd1, dd2, dd3, dd4, dd5;
#define D2OF(JJ, DD)                                                       \
        {                                                                  \
            const float4 s = cb[JJ];                                       \
            const double dx = qdx - (double)s.x;                           \
            const double dy = qdy - (double)s.y;                           \
            const double dz = qdz - (double)s.z;                           \
            DD = fma(dx, dx, fma(dy, dy, dz * dz));                        \
        }
        D2OF(ii0, dd0) D2OF(ii1, dd1) D2OF(ii2, dd2)
        D2OF(ii3, dd3) D2OF(ii4, dd4) D2OF(ii5, dd5)
#undef D2OF

#define CSW(A, B)                                                          \
        {                                                                  \
            const bool sw = (dd##B < dd##A) ||                             \
                            (dd##B == dd##A && ii##B < ii##A);             \
            const double td = sw ? dd##B : dd##A;                          \
            const double tu = sw ? dd##A : dd##B;                          \
            const int    ti = sw ? ii##B : ii##A;                          \
            const int    tj = sw ? ii##A : ii##B;                          \
            dd##A = td; dd##B = tu; ii##A = ti; ii##B = tj;                \
        }
        // optimal 12-comparator sorting network, n=6 (Knuth)
        CSW(0,5) CSW(1,3) CSW(2,4)
        CSW(1,2) CSW(3,4)
        CSW(0,3) CSW(2,5)
        CSW(0,1) CSW(2,3) CSW(4,5)
        CSW(1,2) CSW(3,4)
#undef CSW

        const double w0 = 1.0 / (dd0 + 1e-6);
        const double w1 = 1.0 / (dd1 + 1e-6);
        const double w2 = 1.0 / (dd2 + 1e-6);
        const double inv = 1.0 / (w0 + w1 + w2);
        // safe: only (q, h=0) touches mbuf[q][*] between barriers, and it
        // has already consumed them => in-place publish, no race
        mbuf[q][1][0] = ii0; mbuf[q][1][1] = ii1; mbuf[q][1][2] = ii2;
        mbuf[q][1][3] = __float_as_int((float)(w0 * inv));
        mbuf[q][1][4] = __float_as_int((float)(w1 * inv));
        mbuf[q][1][5] = __float_as_int((float)(w2 * inv));
    }
    __syncthreads();

    // ---- Phase 2: wave-per-query gather-blend (64 lanes x float4 = 256 dims) ----
    {
        const int wv   = tid >> 6;               // 0..3
        const int lane = tid & 63;
        const float4* fb = (const float4*)(feats + (size_t)bl * NS * DIM);
        float* ob = out + ((size_t)bl * NQ + qbase) * DIM;

#pragma unroll 2
        for (int j = wv; j < QPB; j += 4) {
            const int   i0 = mbuf[j][1][0], i1 = mbuf[j][1][1], i2 = mbuf[j][1][2];
            const float w0 = __int_as_float(mbuf[j][1][3]);
            const float w1 = __int_as_float(mbuf[j][1][4]);
            const float w2 = __int_as_float(mbuf[j][1][5]);
            const float4 f0 = fb[(size_t)i0 * (DIM / 4) + lane];
            const float4 f1 = fb[(size_t)i1 * (DIM / 4) + lane];
            const float4 f2 = fb[(size_t)i2 * (DIM / 4) + lane];
            f32x4 r;
            r.x = fmaf(w0, f0.x, fmaf(w1, f1.x, w2 * f2.x));
            r.y = fmaf(w0, f0.y, fmaf(w1, f1.y, w2 * f2.y));
            r.z = fmaf(w0, f0.z, fmaf(w1, f1.z, w2 * f2.z));
            r.w = fmaf(w0, f0.w, fmaf(w1, f1.w, w2 * f2.w));
            __builtin_nontemporal_store(
                r, (f32x4*)(ob + ((size_t)j * DIM) + lane * 4));
        }
    }
}

extern "C" void kernel_launch(void* const* d_in, const int* in_sizes, int n_in,
                              void* d_out, int out_size, void* d_ws, size_t ws_size,
                              hipStream_t stream) {
    const float* xyzs  = nullptr;  // 16*2048*3
    const float* feats = nullptr;  // 16*2048*256
    const float* xyzo  = nullptr;  // 16*8192*3
    for (int i = 0; i < n_in; ++i) {
        if      (in_sizes[i] == NBL * NS * 3)   xyzs  = (const float*)d_in[i];
        else if (in_sizes[i] == NBL * NS * DIM) feats = (const float*)d_in[i];
        else if (in_sizes[i] == NBL * NQ * 3)   xyzo  = (const float*)d_in[i];
    }
    float* out  = (float*)d_out;
    float4* ws4 = (float4*)d_ws;                 // needs 16*2048*16B = 512 KiB

    fprep_kernel<<<dim3((NBL * NS + 255) / 256), dim3(256), 0, stream>>>(xyzs, ws4);
    dim3 grid(NBL * (NQ / QPB));                 // 2048 blocks
    dim3 block(TPB);                             // 256 threads
    fprop_kernel<<<grid, block, 0, stream>>>(ws4, feats, xyzo, out);
}